// Round 5
// baseline (1346.305 us; speedup 1.0000x reference)
//
#include <hip/hip_runtime.h>

#define T_STEPS 16
#define BATCH 16
#define XHW (100*768)                 // one (t,b) image
#define M2_ELEMS (BATCH*32*25*192)    // 2,457,600
#define C4_ELEMS (BATCH*25*192)       // 76,800
#define H3_ELEMS (BATCH*64*25*192)    // 4,915,200
#define M1P_STRIDE 9600               // 3 rows * 16 ch * 200 cols (block-private mem1)
#define M1P_ELEMS (800*M1P_STRIDE)    // 7,680,000

// ================= fused conv1+LIF1 -> conv2+LIF2, one timestep ==============
// Block = (b, mem2-row r, col-half). Owns mem2[b][*][r][c0..c0+95].
// Maintains PRIVATE mem1 state for s1 rows m=2r-1..2r+1, cols gc=2c0-1..2c0+191
// (halo rows/cols recomputed identically by neighbor blocks; private storage ->
// no cross-block read/write race). Spikes live only in LDS.
__global__ __launch_bounds__(256) void k12_step(
    const float* __restrict__ x,     // [B,100,768] timestep slice
    const float* __restrict__ w1,    // [16,1,5,5]
    const float* __restrict__ b1,    // [16]
    const float* __restrict__ w2,    // [32,16,3,3]
    const float* __restrict__ b2,    // [32]
    float* __restrict__ m1p,         // [800][3][16][200] private mem1 tiles
    float* __restrict__ mem2)        // [B,32,25,192]
{
    __shared__ float xs[9][400];             // x tile rows 4r-4..4r+4, cols 4c0-4..
    __shared__ unsigned char s1s[3][16][200]; // spikes, local col lc (gc=2c0-1+lc)
    __shared__ float w1s[400], b1s[16];
    __shared__ float w2s[144*32], b2s[32];   // [r=ic*9+kk][oc]

    const int bx  = blockIdx.x;      // 0..49 : r*2+half
    const int b   = blockIdx.y;      // 0..15
    const int r   = bx >> 1;         // mem2 row
    const int c0  = (bx & 1) * 96;   // mem2 col base
    const int tid = threadIdx.x;

    // ---- stage weights / zero spikes / stage x tile ----
    for (int i = tid; i < 400; i += 256) w1s[i] = w1[i];
    if (tid < 16) b1s[tid] = b1[tid];
    for (int i = tid; i < 4608; i += 256) {
        int oc = i & 31, rr = i >> 5;
        w2s[rr * 32 + oc] = w2[oc * 144 + rr];
    }
    if (tid < 32) b2s[tid] = b2[tid];
    for (int i = tid; i < 2400; i += 256) ((unsigned int*)s1s)[i] = 0u;

    const float* xb = x + b * XHW;
    for (int i = tid; i < 9 * 400; i += 256) {
        int q = i / 400, xc = i % 400;
        int gxr = 4 * r - 4 + q;
        int gxc = 4 * c0 - 4 + xc;
        float v = 0.f;
        if ((unsigned)gxr < 100u && (unsigned)gxc < 768u) v = xb[gxr * 768 + gxc];
        xs[q][xc] = v;
    }
    __syncthreads();

    // ---- conv1 + LIF1 : outputs (i in 0..2, ch in 0..15, lc in 0..192) ----
    // chunk = 5 consecutive lc; 39 chunks per (i,ch); 3*16*39 = 1872 chunks
    float* mp = m1p + (size_t)(b * 50 + bx) * M1P_STRIDE;
    for (int cidx = tid; cidx < 1872; cidx += 256) {
        int i   = cidx / 624;
        int rem = cidx % 624;
        int ch  = rem / 39;
        int ck  = rem % 39;
        int lc0 = ck * 5;
        int m   = 2 * r - 1 + i;
        if (m < 0) continue;                 // r=0,i=0: s1s row stays 0 (pad)
        float wreg[25];
#pragma unroll
        for (int k = 0; k < 25; k++) wreg[k] = w1s[ch * 25 + k];
        float acc[5];
#pragma unroll
        for (int cc = 0; cc < 5; cc++) acc[cc] = b1s[ch];
#pragma unroll
        for (int kh = 0; kh < 5; kh++) {
            int q = 2 * i + kh;              // xs row
            float xv[13];
#pragma unroll
            for (int t = 0; t < 13; t++) xv[t] = xs[q][2 * lc0 + t];
#pragma unroll
            for (int kw = 0; kw < 5; kw++) {
                float w = wreg[kh * 5 + kw];
#pragma unroll
                for (int cc = 0; cc < 5; cc++)
                    acc[cc] = fmaf(xv[2 * cc + kw], w, acc[cc]);
            }
        }
#pragma unroll
        for (int cc = 0; cc < 5; cc++) {
            int lc = lc0 + cc;
            if (lc > 192) continue;          // last chunk tail
            int gc = 2 * c0 - 1 + lc;        // global s1 col
            if (gc < 0) continue;            // c0=0, lc=0 (pad col)
            int idx = (i * 16 + ch) * 200 + lc;
            float mm = mp[idx] * 0.5f + acc[cc];
            bool f = (mm >= 1.0f);
            mp[idx] = f ? 0.f : mm;
            s1s[i][ch][lc] = f ? 1 : 0;
        }
    }
    __syncthreads();

    // ---- conv2 + LIF2 : thread owns (oc = tid>>3, 12 cols chunk = tid&7) ----
    {
        int oc = tid >> 3;
        int cl0 = (tid & 7) * 12;            // local mem2 col base (0..84)
        float acc[12];
#pragma unroll
        for (int cc = 0; cc < 12; cc++) acc[cc] = b2s[oc];
        for (int ic = 0; ic < 16; ic++) {
#pragma unroll
            for (int kh = 0; kh < 3; kh++) {
                const unsigned char* sp = &s1s[kh][ic][2 * cl0];
                float sv[25];
#pragma unroll
                for (int t = 0; t < 25; t++) sv[t] = (float)sp[t];
#pragma unroll
                for (int kw = 0; kw < 3; kw++) {
                    float w = w2s[((ic * 3 + kh) * 3 + kw) * 32 + oc];
#pragma unroll
                    for (int cc = 0; cc < 12; cc++)
                        acc[cc] = fmaf(sv[2 * cc + kw], w, acc[cc]);
                }
            }
        }
        int base = ((b * 32 + oc) * 25 + r) * 192 + c0 + cl0;
#pragma unroll
        for (int cc = 0; cc < 12; cc++) {
            float mm = mem2[base + cc] * 0.5f + acc[cc];
            mem2[base + cc] = (mm >= 1.0f) ? 0.f : mm;
        }
    }
}

// ========== K3: conv3 + bias + relu (2 output rows/thread, float4 w) =========
__global__ __launch_bounds__(192) void k3_conv3_relu(
    const float* __restrict__ mem2,  // [B,32,25,192]
    const float* __restrict__ w3,    // [64,32,3,3]
    const float* __restrict__ b3,    // [64]
    float* __restrict__ h)           // [B,64,25,192]
{
    __shared__ float wsm[288 * 16];  // [r=ic*9+kk][oc_local 16]
    __shared__ float bsm[16];
    int ocbase = blockIdx.y * 16;
    for (int i = threadIdx.x; i < 4608; i += 192) {
        int o = i & 15, rr = i >> 4;
        wsm[i] = w3[(ocbase + o) * 288 + rr];
    }
    if (threadIdx.x < 16) bsm[threadIdx.x] = b3[ocbase + threadIdx.x];
    __syncthreads();

    int j   = threadIdx.x;           // col 0..191
    int bx  = blockIdx.x;            // b*13 + ohp
    int b   = bx / 13, ohp = bx % 13;
    int oh0 = ohp * 2;
    bool r1ok = (oh0 + 1) < 25;

    float acc0[16], acc1[16];
#pragma unroll
    for (int o = 0; o < 16; o++) { acc0[o] = bsm[o]; acc1[o] = bsm[o]; }

    const float* mb = mem2 + b * (32 * 25 * 192);
    for (int ic = 0; ic < 32; ic++) {
        const float* mc = mb + ic * (25 * 192);
        float rw[4][3];
#pragma unroll
        for (int q = 0; q < 4; q++) {
            int ih = oh0 - 1 + q;
            bool okh = (unsigned)ih < 25u;
#pragma unroll
            for (int c = 0; c < 3; c++) {
                int iw = j - 1 + c;
                rw[q][c] = (okh && (unsigned)iw < 192u) ? mc[ih * 192 + iw] : 0.f;
            }
        }
#pragma unroll
        for (int kh = 0; kh < 3; kh++) {
#pragma unroll
            for (int kw = 0; kw < 3; kw++) {
                const float4* wp = (const float4*)&wsm[((ic * 3 + kh) * 3 + kw) * 16];
                float v0 = rw[kh][kw], v1 = rw[kh + 1][kw];
#pragma unroll
                for (int g = 0; g < 4; g++) {
                    float4 wv = wp[g];
                    acc0[g*4+0] = fmaf(v0, wv.x, acc0[g*4+0]);
                    acc0[g*4+1] = fmaf(v0, wv.y, acc0[g*4+1]);
                    acc0[g*4+2] = fmaf(v0, wv.z, acc0[g*4+2]);
                    acc0[g*4+3] = fmaf(v0, wv.w, acc0[g*4+3]);
                    acc1[g*4+0] = fmaf(v1, wv.x, acc1[g*4+0]);
                    acc1[g*4+1] = fmaf(v1, wv.y, acc1[g*4+1]);
                    acc1[g*4+2] = fmaf(v1, wv.z, acc1[g*4+2]);
                    acc1[g*4+3] = fmaf(v1, wv.w, acc1[g*4+3]);
                }
            }
        }
    }
#pragma unroll
    for (int o = 0; o < 16; o++) {
        int idx = ((b * 64 + ocbase + o) * 25 + oh0) * 192 + j;
        h[idx] = fmaxf(acc0[o], 0.f);
        if (r1ok) h[idx + 192] = fmaxf(acc1[o], 0.f);
    }
}

// ========== K4: conv4 partials (16-ic slice per blockIdx.y, atomicAdd) =======
__global__ __launch_bounds__(256) void k4_conv4(
    const float* __restrict__ h,    // [B,64,25,192]
    const float* __restrict__ w4,   // [1,64,3,3]
    float* __restrict__ c4)         // [B,25,192] (pre-zeroed; bias in k5)
{
    __shared__ float wsm[144];
    int icbase = blockIdx.y * 16;
    for (int i = threadIdx.x; i < 144; i += 256) wsm[i] = w4[icbase * 9 + i];
    __syncthreads();

    int gid = blockIdx.x * 256 + threadIdx.x;
    int ow = gid % 192;
    int t2 = gid / 192;
    int oh = t2 % 25;
    int b  = t2 / 25;

    float acc = 0.f;
    const float* hb = h + (b * 64 + icbase) * (25 * 192);
    for (int ic = 0; ic < 16; ic++) {
        const float* hc = hb + ic * (25 * 192);
#pragma unroll
        for (int kh = 0; kh < 3; kh++) {
            int ih = oh - 1 + kh;
            bool okh = (unsigned)ih < 25u;
#pragma unroll
            for (int kw = 0; kw < 3; kw++) {
                int iw = ow - 1 + kw;
                float v = (okh && (unsigned)iw < 192u) ? hc[ih * 192 + iw] : 0.f;
                acc = fmaf(v, wsm[ic * 9 + kh * 3 + kw], acc);
            }
        }
    }
    atomicAdd(&c4[gid], acc);
}

// ========== K5: + bias, bilinear x4 (align_corners=False), softplus ==========
__global__ __launch_bounds__(256) void k5_resize_softplus(
    const float* __restrict__ c4,   // [B,25,192]
    const float* __restrict__ b4,   // [1]
    float* __restrict__ out)        // [B,100,768]
{
    int gid = blockIdx.x * 256 + threadIdx.x;
    int ox = gid % 768;
    int t2 = gid / 768;
    int oy = t2 % 100;
    int b  = t2 / 100;

    float bias = b4[0];
    float sy = (oy + 0.5f) * 0.25f - 0.5f;
    float sx = (ox + 0.5f) * 0.25f - 0.5f;
    int y0 = (int)floorf(sy); float fy = sy - (float)y0;
    int x0 = (int)floorf(sx); float fx = sx - (float)x0;
    int y1 = y0 + 1, x1 = x0 + 1;
    y0 = y0 < 0 ? 0 : (y0 > 24 ? 24 : y0);
    y1 = y1 < 0 ? 0 : (y1 > 24 ? 24 : y1);
    x0 = x0 < 0 ? 0 : (x0 > 191 ? 191 : x0);
    x1 = x1 < 0 ? 0 : (x1 > 191 ? 191 : x1);

    const float* cb = c4 + b * 4800;
    float v00 = cb[y0 * 192 + x0] + bias, v01 = cb[y0 * 192 + x1] + bias;
    float v10 = cb[y1 * 192 + x0] + bias, v11 = cb[y1 * 192 + x1] + bias;
    float v = (1.f - fy) * ((1.f - fx) * v00 + fx * v01)
            +        fy  * ((1.f - fx) * v10 + fx * v11);
    out[gid] = fmaxf(v, 0.f) + log1pf(expf(-fabsf(v)));
}

extern "C" void kernel_launch(void* const* d_in, const int* in_sizes, int n_in,
                              void* d_out, int out_size, void* d_ws, size_t ws_size,
                              hipStream_t stream) {
    const float* x_seq = (const float*)d_in[0];
    const float* w1 = (const float*)d_in[1];
    const float* b1 = (const float*)d_in[2];
    const float* w2 = (const float*)d_in[3];
    const float* b2 = (const float*)d_in[4];
    const float* w3 = (const float*)d_in[5];
    const float* b3 = (const float*)d_in[6];
    const float* w4 = (const float*)d_in[7];
    const float* b4 = (const float*)d_in[8];
    float* out = (float*)d_out;

    // ws layout (floats): [m1p 7,680,000][mem2 2,457,600][c4 76,800][h 4,915,200]
    float* ws   = (float*)d_ws;
    float* m1p  = ws;
    float* mem2 = ws + M1P_ELEMS;
    float* c4o  = ws + M1P_ELEMS + M2_ELEMS;
    float* h    = ws + M1P_ELEMS + M2_ELEMS + C4_ELEMS;

    // zero state (m1p + mem2 + c4 contiguous, ~41 MB)
    hipMemsetAsync(m1p, 0, (size_t)(M1P_ELEMS + M2_ELEMS + C4_ELEMS) * sizeof(float), stream);

    for (int t = 0; t < T_STEPS; t++) {
        const float* xt = x_seq + (size_t)t * BATCH * XHW;
        k12_step<<<dim3(50, 16), 256, 0, stream>>>(xt, w1, b1, w2, b2, m1p, mem2);
    }
    k3_conv3_relu<<<dim3(16 * 13, 4), 192, 0, stream>>>(mem2, w3, b3, h);
    k4_conv4<<<dim3(300, 4), 256, 0, stream>>>(h, w4, c4o);
    k5_resize_softplus<<<4800, 256, 0, stream>>>(c4o, b4, out);
}

// Round 6
// 789.110 us; speedup vs baseline: 1.7061x; 1.7061x over previous
//
#include <hip/hip_runtime.h>

#define T_STEPS 16
#define BATCH 16
#define XHW (100*768)
#define M2_ELEMS (BATCH*32*25*192)    // 2,457,600
#define C4_ELEMS (BATCH*25*192)       // 76,800
#define H3_ELEMS (BATCH*64*25*192)    // 4,915,200

// ===================== persistent fused scan kernel ==========================
// Block = (b, rg 0..12, wseg 0..5). Owns mem2 rows 2rg..2rg+1, cols c0..c0+31.
// Private mem1 (registers) for s1 rows 4rg-1..4rg+3, cols gc=2c0-1..2c0+64
// (66 cols). Halo rows/cols recomputed identically by neighbor blocks.
// Per step: stage x tile -> sync -> conv1+LIF1 (write spikes f32 to LDS)
// -> sync -> conv2+LIF2 (mem2 in registers). Two barriers/step.
__global__ __launch_bounds__(256) void k_scan(
    const float* __restrict__ x_seq, // [T,B,100,768]
    const float* __restrict__ w1,    // [16,1,5,5]
    const float* __restrict__ b1,    // [16]
    const float* __restrict__ w2,    // [32,16,3,3]
    const float* __restrict__ b2,    // [32]
    float* __restrict__ mem2)        // [B,32,25,192] final state out
{
    __shared__ float s1s[5][16][72];  // spike tile, cols lc (gc=2c0-1+lc), pad 72
    __shared__ float xs[13][136];     // x rows 8rg-4..8rg+8, cols 4c0-4+xc
    __shared__ float w2s[4608];       // [r=ic*9+kh*3+kw][oc]
    __shared__ float b2s[32];

    const int tid  = threadIdx.x;
    const int bxx  = blockIdx.x;      // wseg*13 + rg
    const int b    = blockIdx.y;
    const int wseg = bxx / 13;
    const int rg   = bxx % 13;
    const int c0   = wseg * 32;

    // ---- one-time staging ----
    for (int i = tid; i < 4608; i += 256) {
        int o = i & 31, r = i >> 5;
        w2s[i] = w2[o * 144 + r];     // w2s[r*32+o] ... i == r*32+o
    }
    if (tid < 32) b2s[tid] = b2[tid];
    for (int i = tid; i < 5 * 16 * 72; i += 256) ((float*)s1s)[i] = 0.f;

    // conv1 per-thread statics: 16 lanes share (row,chunk); ch = lane&15
    const int ch = tid & 15;
    const int ig = tid >> 4;          // item-group 0..15
    float w1reg[25];
#pragma unroll
    for (int k = 0; k < 25; k++) w1reg[k] = w1[ch * 25 + k];
    const float b1reg = b1[ch];

    // conv2 per-thread statics: oc 0..31, r2 0..1, ch4 0..3 (8 cols each)
    const int oc   = tid >> 3;
    const int r2   = (tid >> 2) & 1;
    const int ch4  = tid & 3;
    const int r_out = 2 * rg + r2;
    const bool c2ok = (r_out < 25);
    const float bias2 = b2s[0] * 0.f; // placeholder; real bias read after sync below

    float m1reg[3][8];
#pragma unroll
    for (int k = 0; k < 3; k++)
#pragma unroll
        for (int c = 0; c < 8; c++) m1reg[k][c] = 0.f;
    float mem2reg[8];
#pragma unroll
    for (int c = 0; c < 8; c++) mem2reg[c] = 0.f;

    for (int t = 0; t < T_STEPS; t++) {
        // ---- stage x tile for this timestep ----
        const float* xb = x_seq + ((size_t)t * BATCH + b) * XHW;
        for (int i = tid; i < 13 * 136; i += 256) {
            int q = i / 136, xc = i % 136;
            int gxr = 8 * rg - 4 + q;
            int gxc = 4 * c0 - 4 + xc;
            float v = 0.f;
            if ((unsigned)gxr < 100u && (unsigned)gxc < 768u) v = xb[gxr * 768 + gxc];
            xs[q][xc] = v;
        }
        __syncthreads();   // xs ready; prev conv2 done with s1s

        // ---- conv1 + LIF1: items (i row 0..4, cn chunk 0..8) x ch ----
#pragma unroll
        for (int k = 0; k < 3; k++) {
            int item = ig + 16 * k;
            if (item < 45) {
                int i  = item / 9;
                int cn = item % 9;
                int m  = 4 * rg - 1 + i;
                if (m >= 0 && m <= 49) {
                    float acc[8];
#pragma unroll
                    for (int c = 0; c < 8; c++) acc[c] = b1reg;
#pragma unroll
                    for (int kh = 0; kh < 5; kh++) {
                        const float* xr = &xs[2 * i + kh][16 * cn];
                        float4 v0 = *(const float4*)(xr);
                        float4 v1 = *(const float4*)(xr + 4);
                        float4 v2 = *(const float4*)(xr + 8);
                        float4 v3 = *(const float4*)(xr + 12);
                        float4 v4 = *(const float4*)(xr + 16);
                        float xv[20] = {v0.x, v0.y, v0.z, v0.w,
                                        v1.x, v1.y, v1.z, v1.w,
                                        v2.x, v2.y, v2.z, v2.w,
                                        v3.x, v3.y, v3.z, v3.w,
                                        v4.x, v4.y, v4.z, v4.w};
#pragma unroll
                        for (int kw = 0; kw < 5; kw++) {
                            float w = w1reg[kh * 5 + kw];
#pragma unroll
                            for (int c = 0; c < 8; c++)
                                acc[c] = fmaf(xv[2 * c + kw], w, acc[c]);
                        }
                    }
                    int lcb = 8 * cn;
#pragma unroll
                    for (int c = 0; c < 8; c++) {
                        int lc = lcb + c;
                        int gc = 2 * c0 - 1 + lc;
                        if (lc < 66 && (unsigned)gc < 384u) {
                            float mn = m1reg[k][c] * 0.5f + acc[c];
                            bool f = (mn >= 1.0f);
                            s1s[i][ch][lc] = f ? 1.f : 0.f;
                            m1reg[k][c] = f ? 0.f : mn;
                        }
                    }
                }
            }
        }
        __syncthreads();   // spikes ready

        // ---- conv2 + LIF2 (mem2 in registers) ----
        if (c2ok) {
            float acc[8];
#pragma unroll
            for (int c = 0; c < 8; c++) acc[c] = 0.f;
            for (int ic = 0; ic < 16; ic++) {
#pragma unroll
                for (int kh = 0; kh < 3; kh++) {
                    const float* sp = &s1s[2 * r2 + kh][ic][16 * ch4];
                    float4 a0 = *(const float4*)(sp);
                    float4 a1 = *(const float4*)(sp + 4);
                    float4 a2 = *(const float4*)(sp + 8);
                    float4 a3 = *(const float4*)(sp + 12);
                    float4 a4 = *(const float4*)(sp + 16);
                    float sv[20] = {a0.x, a0.y, a0.z, a0.w,
                                    a1.x, a1.y, a1.z, a1.w,
                                    a2.x, a2.y, a2.z, a2.w,
                                    a3.x, a3.y, a3.z, a3.w,
                                    a4.x, a4.y, a4.z, a4.w};
                    const float* wp = &w2s[((ic * 3 + kh) * 3) * 32 + oc];
                    float wk0 = wp[0], wk1 = wp[32], wk2 = wp[64];
#pragma unroll
                    for (int c = 0; c < 8; c++) {
                        float s = fmaf(sv[2 * c], wk0,
                                  fmaf(sv[2 * c + 1], wk1,
                                       sv[2 * c + 2] * wk2));
                        acc[c] += s;
                    }
                }
            }
            float bb = b2s[oc];
#pragma unroll
            for (int c = 0; c < 8; c++) {
                float mn = mem2reg[c] * 0.5f + (acc[c] + bb);
                mem2reg[c] = (mn >= 1.0f) ? 0.f : mn;
            }
        }
        __syncthreads();   // conv2 done with s1s before next overwrite
    }

    // ---- write final mem2 ----
    if (c2ok) {
        int base = ((b * 32 + oc) * 25 + r_out) * 192 + c0 + 8 * ch4;
#pragma unroll
        for (int c = 0; c < 8; c++) mem2[base + c] = mem2reg[c];
    }
    (void)bias2;
}

// ========== K3: conv3 + bias + relu (2 output rows/thread, float4 w) =========
__global__ __launch_bounds__(192) void k3_conv3_relu(
    const float* __restrict__ mem2,  // [B,32,25,192]
    const float* __restrict__ w3,    // [64,32,3,3]
    const float* __restrict__ b3,    // [64]
    float* __restrict__ h)           // [B,64,25,192]
{
    __shared__ float wsm[288 * 16];  // [r=ic*9+kk][oc_local 16]
    __shared__ float bsm[16];
    int ocbase = blockIdx.y * 16;
    for (int i = threadIdx.x; i < 4608; i += 192) {
        int o = i & 15, rr = i >> 4;
        wsm[i] = w3[(ocbase + o) * 288 + rr];
    }
    if (threadIdx.x < 16) bsm[threadIdx.x] = b3[ocbase + threadIdx.x];
    __syncthreads();

    int j   = threadIdx.x;           // col 0..191
    int bx  = blockIdx.x;            // b*13 + ohp
    int b   = bx / 13, ohp = bx % 13;
    int oh0 = ohp * 2;
    bool r1ok = (oh0 + 1) < 25;

    float acc0[16], acc1[16];
#pragma unroll
    for (int o = 0; o < 16; o++) { acc0[o] = bsm[o]; acc1[o] = bsm[o]; }

    const float* mb = mem2 + b * (32 * 25 * 192);
    for (int ic = 0; ic < 32; ic++) {
        const float* mc = mb + ic * (25 * 192);
        float rw[4][3];
#pragma unroll
        for (int q = 0; q < 4; q++) {
            int ih = oh0 - 1 + q;
            bool okh = (unsigned)ih < 25u;
#pragma unroll
            for (int c = 0; c < 3; c++) {
                int iw = j - 1 + c;
                rw[q][c] = (okh && (unsigned)iw < 192u) ? mc[ih * 192 + iw] : 0.f;
            }
        }
#pragma unroll
        for (int kh = 0; kh < 3; kh++) {
#pragma unroll
            for (int kw = 0; kw < 3; kw++) {
                const float4* wp = (const float4*)&wsm[((ic * 3 + kh) * 3 + kw) * 16];
                float v0 = rw[kh][kw], v1 = rw[kh + 1][kw];
#pragma unroll
                for (int g = 0; g < 4; g++) {
                    float4 wv = wp[g];
                    acc0[g*4+0] = fmaf(v0, wv.x, acc0[g*4+0]);
                    acc0[g*4+1] = fmaf(v0, wv.y, acc0[g*4+1]);
                    acc0[g*4+2] = fmaf(v0, wv.z, acc0[g*4+2]);
                    acc0[g*4+3] = fmaf(v0, wv.w, acc0[g*4+3]);
                    acc1[g*4+0] = fmaf(v1, wv.x, acc1[g*4+0]);
                    acc1[g*4+1] = fmaf(v1, wv.y, acc1[g*4+1]);
                    acc1[g*4+2] = fmaf(v1, wv.z, acc1[g*4+2]);
                    acc1[g*4+3] = fmaf(v1, wv.w, acc1[g*4+3]);
                }
            }
        }
    }
#pragma unroll
    for (int o = 0; o < 16; o++) {
        int idx = ((b * 64 + ocbase + o) * 25 + oh0) * 192 + j;
        h[idx] = fmaxf(acc0[o], 0.f);
        if (r1ok) h[idx + 192] = fmaxf(acc1[o], 0.f);
    }
}

// ========== K4: conv4 partials (16-ic slice per blockIdx.y, atomicAdd) =======
__global__ __launch_bounds__(256) void k4_conv4(
    const float* __restrict__ h,    // [B,64,25,192]
    const float* __restrict__ w4,   // [1,64,3,3]
    float* __restrict__ c4)         // [B,25,192] (pre-zeroed; bias in k5)
{
    __shared__ float wsm[144];
    int icbase = blockIdx.y * 16;
    for (int i = threadIdx.x; i < 144; i += 256) wsm[i] = w4[icbase * 9 + i];
    __syncthreads();

    int gid = blockIdx.x * 256 + threadIdx.x;
    int ow = gid % 192;
    int t2 = gid / 192;
    int oh = t2 % 25;
    int b  = t2 / 25;

    float acc = 0.f;
    const float* hb = h + (b * 64 + icbase) * (25 * 192);
    for (int ic = 0; ic < 16; ic++) {
        const float* hc = hb + ic * (25 * 192);
#pragma unroll
        for (int kh = 0; kh < 3; kh++) {
            int ih = oh - 1 + kh;
            bool okh = (unsigned)ih < 25u;
#pragma unroll
            for (int kw = 0; kw < 3; kw++) {
                int iw = ow - 1 + kw;
                float v = (okh && (unsigned)iw < 192u) ? hc[ih * 192 + iw] : 0.f;
                acc = fmaf(v, wsm[ic * 9 + kh * 3 + kw], acc);
            }
        }
    }
    atomicAdd(&c4[gid], acc);
}

// ========== K5: + bias, bilinear x4 (align_corners=False), softplus ==========
__global__ __launch_bounds__(256) void k5_resize_softplus(
    const float* __restrict__ c4,   // [B,25,192]
    const float* __restrict__ b4,   // [1]
    float* __restrict__ out)        // [B,100,768]
{
    int gid = blockIdx.x * 256 + threadIdx.x;
    int ox = gid % 768;
    int t2 = gid / 768;
    int oy = t2 % 100;
    int b  = t2 / 100;

    float bias = b4[0];
    float sy = (oy + 0.5f) * 0.25f - 0.5f;
    float sx = (ox + 0.5f) * 0.25f - 0.5f;
    int y0 = (int)floorf(sy); float fy = sy - (float)y0;
    int x0 = (int)floorf(sx); float fx = sx - (float)x0;
    int y1 = y0 + 1, x1 = x0 + 1;
    y0 = y0 < 0 ? 0 : (y0 > 24 ? 24 : y0);
    y1 = y1 < 0 ? 0 : (y1 > 24 ? 24 : y1);
    x0 = x0 < 0 ? 0 : (x0 > 191 ? 191 : x0);
    x1 = x1 < 0 ? 0 : (x1 > 191 ? 191 : x1);

    const float* cb = c4 + b * 4800;
    float v00 = cb[y0 * 192 + x0] + bias, v01 = cb[y0 * 192 + x1] + bias;
    float v10 = cb[y1 * 192 + x0] + bias, v11 = cb[y1 * 192 + x1] + bias;
    float v = (1.f - fy) * ((1.f - fx) * v00 + fx * v01)
            +        fy  * ((1.f - fx) * v10 + fx * v11);
    out[gid] = fmaxf(v, 0.f) + log1pf(expf(-fabsf(v)));
}

extern "C" void kernel_launch(void* const* d_in, const int* in_sizes, int n_in,
                              void* d_out, int out_size, void* d_ws, size_t ws_size,
                              hipStream_t stream) {
    const float* x_seq = (const float*)d_in[0];
    const float* w1 = (const float*)d_in[1];
    const float* b1 = (const float*)d_in[2];
    const float* w2 = (const float*)d_in[3];
    const float* b2 = (const float*)d_in[4];
    const float* w3 = (const float*)d_in[5];
    const float* b3 = (const float*)d_in[6];
    const float* w4 = (const float*)d_in[7];
    const float* b4 = (const float*)d_in[8];
    float* out = (float*)d_out;

    // ws layout (floats): [mem2 M2][c4 C4][h H3]
    float* ws   = (float*)d_ws;
    float* mem2 = ws;
    float* c4o  = ws + M2_ELEMS;
    float* h    = ws + M2_ELEMS + C4_ELEMS;

    // only c4 needs zeroing (atomic accumulation target)
    hipMemsetAsync(c4o, 0, (size_t)C4_ELEMS * sizeof(float), stream);

    k_scan<<<dim3(78, 16), 256, 0, stream>>>(x_seq, w1, b1, w2, b2, mem2);
    k3_conv3_relu<<<dim3(16 * 13, 4), 192, 0, stream>>>(mem2, w3, b3, h);
    k4_conv4<<<dim3(300, 4), 256, 0, stream>>>(h, w4, c4o);
    k5_resize_softplus<<<4800, 256, 0, stream>>>(c4o, b4, out);
}